// Round 1
// baseline (3365.815 us; speedup 1.0000x reference)
//
#include <hip/hip_runtime.h>

#define BD 256   // batch
#define HD 1024  // hidden
#define KC 2048  // concatenated K = [x | h]
#define LATD 512 // latent
#define OD 128   // output dim
#define TS 100   // seq_len (fixed by problem)

typedef __attribute__((ext_vector_type(8))) short s16x8;
typedef __attribute__((ext_vector_type(4))) float f32x4;

__device__ __forceinline__ float b2f(short s) {
  return __uint_as_float(((unsigned)(unsigned short)s) << 16);
}
__device__ __forceinline__ short f2b(float f) {
  unsigned u = __float_as_uint(f);
  u += 0x7fff + ((u >> 16) & 1);  // RNE
  return (short)(u >> 16);
}
__device__ __forceinline__ float sigm(float x) { return 1.f / (1.f + __expf(-x)); }
__device__ __forceinline__ float tanh_f(float x) { return 1.f - 2.f / (__expf(2.f * x) + 1.f); }

// xh fragment-major chunk index: m -> (mt=m/16, r=m%16), k -> (kc=k/8, e=k%8)
// kq=kc/64, it=(kc/4)%16, q=kc%4; chunk = ((mt*4+kq)*16+it)*64 + q*16 + r
__device__ __forceinline__ size_t xhf_idx(int m, int k) {
  int kc = k >> 3;
  int kq = kc >> 6, it = (kc >> 2) & 15, q = kc & 3;
  int mt = m >> 4, r = m & 15;
  return ((((size_t)mt * 4 + kq) * 16 + it) * 64 + q * 16 + r) * 8 + (k & 7);
}

// ---------------- one-time prep kernels ----------------

__global__ __launch_bounds__(256) void cvt8_k(const float* __restrict__ in,
                                              short* __restrict__ out) {
  int i = (blockIdx.x * 256 + threadIdx.x) * 8;
  f32x4 a = *(const f32x4*)(in + i), b = *(const f32x4*)(in + i + 4);
  s16x8 o;
#pragma unroll
  for (int e = 0; e < 4; ++e) { o[e] = f2b(a[e]); o[4 + e] = f2b(b[e]); }
  *(s16x8*)(out + i) = o;
}

// Fragment-major weight repack (verified r6):
// chunk i = ((bn*64 + kit)*4 + quad)*16 + lan; bn = g*64+bx; k = kit*32+quad*8
__global__ __launch_bounds__(256) void wrep_k(const float* __restrict__ Wih,
                                              const float* __restrict__ Whh,
                                              short* __restrict__ Wt) {
  int i = blockIdx.x * 256 + threadIdx.x;  // chunk id, < 1048576
  int lan = i & 15, quad = (i >> 4) & 3, kit = (i >> 6) & 63, bn = i >> 12;
  int g = bn >> 6, bx = bn & 63;
  int n = g * HD + bx * 16 + lan;
  int k = kit * 32 + quad * 8;
  const float* src = (k < HD) ? (Wih + (size_t)n * HD + k)
                              : (Whh + (size_t)n * HD + (k - HD));
  f32x4 a = *(const f32x4*)src, b = *(const f32x4*)(src + 4);
  s16x8 o;
#pragma unroll
  for (int e = 0; e < 4; ++e) { o[e] = f2b(a[e]); o[4 + e] = f2b(b[e]); }
  *(s16x8*)(Wt + (size_t)i * 8) = o;
}

__global__ __launch_bounds__(256) void bsum_k(const float* __restrict__ bi,
                                              const float* __restrict__ bh,
                                              float* __restrict__ bs) {
  int i = blockIdx.x * 256 + threadIdx.x;
  bs[i] = bi[i] + bh[i];
}

__global__ __launch_bounds__(256) void x0_k(const float* __restrict__ st,
                                            const float* __restrict__ W,
                                            const float* __restrict__ bias,
                                            short* __restrict__ xrow) {
  int j = blockIdx.x * 256 + threadIdx.x;
  float acc = 0.f;
  for (int k = 0; k < OD; ++k) acc += st[k] * W[j * OD + k];
  acc += bias[j];
  xrow[j] = f2b(acc > 0.f ? acc : 0.f);
}

// x-half init: xhf[m][k] = xrow[k], k<1024
__global__ __launch_bounds__(256) void bcast_k(const short* __restrict__ xrow,
                                               short* __restrict__ xhf) {
  int i = blockIdx.x * 256 + threadIdx.x;  // over BD*HD
  int m = i >> 10, k = i & 1023;
  xhf[xhf_idx(m, k)] = xrow[k];
}

__global__ void zero_ctr_k(unsigned* __restrict__ c) { c[threadIdx.x] = 0u; }

// ---------------- head GEMM: out = lrelu(A @ W^T + b), N=1024, M=256 ----------------
// MODE: 0 = fp32 flat [m*1024+col]; 1 = bf16 flat [m*os+oo+col]; 2 = bf16 xhf h-half
template <int K, bool IN_BF16, int MODE>
__global__ __launch_bounds__(256) void fc_mfma(const void* __restrict__ in_,
                                               const float* __restrict__ W,
                                               const float* __restrict__ bias,
                                               void* __restrict__ out_,
                                               int ostride, int ooff) {
  const int tid = threadIdx.x;
  const int w = tid >> 6, lan = tid & 15, quad = (tid & 63) >> 4;
  const int n0 = blockIdx.x * 64;
  const int m0 = blockIdx.y * 64;
  const int arow = m0 + w * 16 + lan;
  f32x4 acc[4] = {};
  for (int k0 = 0; k0 < K; k0 += 32) {
    const int ka = k0 + quad * 8;
    s16x8 af;
    if (IN_BF16) {
      af = *(const s16x8*)((const short*)in_ + arow * K + ka);
    } else {
      const float* ap = (const float*)in_ + arow * K + ka;
      f32x4 a0 = *(const f32x4*)ap, a1 = *(const f32x4*)(ap + 4);
#pragma unroll
      for (int e = 0; e < 4; ++e) { af[e] = f2b(a0[e]); af[4 + e] = f2b(a1[e]); }
    }
#pragma unroll
    for (int nf = 0; nf < 4; ++nf) {
      const float* bp = W + (n0 + nf * 16 + lan) * K + ka;
      f32x4 b0 = *(const f32x4*)bp, b1 = *(const f32x4*)(bp + 4);
      s16x8 bf;
#pragma unroll
      for (int e = 0; e < 4; ++e) { bf[e] = f2b(b0[e]); bf[4 + e] = f2b(b1[e]); }
      acc[nf] = __builtin_amdgcn_mfma_f32_16x16x32_bf16(af, bf, acc[nf], 0, 0, 0);
    }
  }
#pragma unroll
  for (int nf = 0; nf < 4; ++nf) {
    int col = n0 + nf * 16 + lan;
    float bb = bias[col];
#pragma unroll
    for (int j = 0; j < 4; ++j) {
      int m = m0 + w * 16 + quad * 4 + j;
      float v = acc[nf][j] + bb;
      v = v > 0.f ? v : 0.01f * v;
      if (MODE == 0)
        ((float*)out_)[m * 1024 + col] = v;
      else if (MODE == 1)
        ((short*)out_)[m * ostride + ooff + col] = f2b(v);
      else
        ((short*)out_)[xhf_idx(m, HD + col)] = f2b(v);
    }
  }
}

__global__ __launch_bounds__(256) void num_k(const float* __restrict__ n1,
                                             const float* __restrict__ w2,
                                             const float* __restrict__ b2,
                                             float* __restrict__ out) {
  int l = threadIdx.x & 63, w = threadIdx.x >> 6;
  int m = blockIdx.x * 4 + w;
  const float* r = n1 + m * HD + l * 16;
  const float* wv = w2 + l * 16;
  float acc = 0.f;
#pragma unroll
  for (int c = 0; c < 4; ++c) {
    f32x4 a = *(const f32x4*)(r + c * 4), b = *(const f32x4*)(wv + c * 4);
#pragma unroll
    for (int e = 0; e < 4; ++e) acc += a[e] * b[e];
  }
  for (int off = 32; off; off >>= 1) acc += __shfl_down(acc, off);
  if (l == 0) {
    float v = acc + b2[0];
    out[m] = v > 0.f ? v : 0.f;
  }
}

__global__ __launch_bounds__(256) void mass_k(const short* __restrict__ m2,
                                              const float* __restrict__ w3,
                                              const float* __restrict__ b3,
                                              float* __restrict__ out) {
  int l = threadIdx.x & 63, w = threadIdx.x >> 6;
  int m = blockIdx.x * 4 + w;
  const short* r = m2 + m * HD + l * 16;
  s16x8 v0 = *(const s16x8*)r, v1 = *(const s16x8*)(r + 8);
  float z0 = 0.f, z1 = 0.f;
#pragma unroll
  for (int e = 0; e < 8; ++e) {
    float a = b2f(v0[e]), b = b2f(v1[e]);
    z0 += a * w3[l * 16 + e] + b * w3[l * 16 + 8 + e];
    z1 += a * w3[HD + l * 16 + e] + b * w3[HD + l * 16 + 8 + e];
  }
  for (int off = 32; off; off >>= 1) {
    z0 += __shfl_down(z0, off);
    z1 += __shfl_down(z1, off);
  }
  if (l == 0) {
    z0 += b3[0]; z1 += b3[1];
    float mx = fmaxf(z0, z1);
    float e0 = __expf(z0 - mx), e1 = __expf(z1 - mx);
    float s = e0 + e1;
    out[m * 2] = e0 / s;
    out[m * 2 + 1] = e1 / s;
  }
}

// ---------------- persistent LSTM kernel ----------------
// Grid (64,4) = 256 blocks, 512 threads (8 waves). One block per CU, enforced by
// 128 KB static LDS (2 blocks would need 256 KB > 160 KB/CU) -> all blocks co-resident.
// All 4*H x 2048 gate weights live in VGPRs (128 VGPR/thread). Per step only the
// activation tile streams via global_load_lds into a double-buffered LDS pipeline.
// Cross-step sync: per-by (row-group) grid barrier, 64 arrivals each, device-scope
// atomics + __threadfence (wbl2/inv handles XCD L2 non-coherence).

#define MF(a, b, c) __builtin_amdgcn_mfma_f32_16x16x32_bf16(a, b, c, 0, 0, 0)

typedef __attribute__((address_space(1))) const void gas_void;
typedef __attribute__((address_space(3))) void las_void;

__device__ __forceinline__ void grid_bar(unsigned* c, unsigned target) {
  __syncthreads();  // drains vmcnt/lgkmcnt: all this block's stores are in L2
  if (threadIdx.x == 0) {
    __threadfence();                                   // release: wbl2 to coherence point
    atomicAdd(c, 1u);                                  // device-scope arrive
    while (atomicAdd(c, 0u) < target)                  // coherent RMW poll
      __builtin_amdgcn_s_sleep(2);
    __threadfence();                                   // acquire: invalidate stale L1/L2
  }
  __syncthreads();
}

__global__ __launch_bounds__(512, 2) void lstm_persist(
    short* __restrict__ xhA, short* __restrict__ xhB, float* __restrict__ cbuf,
    const short* __restrict__ Wt, const float* __restrict__ bsum,
    short* __restrict__ hsC, const short* __restrict__ outw,
    const float* __restrict__ outb, float* __restrict__ dout,
    float* __restrict__ o_h, float* __restrict__ o_c,
    unsigned* ctr, int CH) {
  __shared__ __align__(16) short sm[65536];  // 128 KB: 2 x 64 KB chunk dbuf / red / phase

  const int tid = threadIdx.x;
  const int w = tid >> 6, l = tid & 63;
  const int w4 = w & 3, gp = w >> 2;     // wave = (K-interleave, gate-pair)
  const int bx = blockIdx.x, by = blockIdx.y;
  const int q = l >> 4, r = l & 15;

  // ---- one-time weight preload: 32 frags = 128 VGPR/thread ----
  // frag (c,jj,gi): gate g = gp*2+gi, kit = c*16 + w4 + 4*jj
  s16x8 W[32];
#pragma unroll
  for (int c = 0; c < 4; ++c)
#pragma unroll
    for (int jj = 0; jj < 4; ++jj)
#pragma unroll
      for (int gi = 0; gi < 2; ++gi) {
        const int g = gp * 2 + gi;
        const int kit = c * 16 + w4 + 4 * jj;
        const size_t bn = (size_t)(g * 64 + bx);
        W[c * 8 + jj * 2 + gi] =
            *(const s16x8*)(Wt + ((bn * 64 + kit) * 64 + l) * 8);
      }

  const int mloc0 = tid >> 4, hc = tid & 15;
  const int chh = bx * 16 + hc;
  float* red = (float*)sm;
  int tslot = 0;
  unsigned pcnt = 0;

  for (int t = 0; t < TS; ++t) {
    const short* src = (t & 1) ? xhB : xhA;
    short* dst = (t & 1) ? xhA : xhB;

    f32x4 c00 = {}, c01 = {}, c10 = {}, c11 = {};
    f32x4 c20 = {}, c21 = {}, c30 = {}, c31 = {};

    // stage chunk 0 (8 frags/wave, 1 KB each)
#pragma unroll
    for (int j = 0; j < 8; ++j) {
      const int fi = w * 8 + j;
      const int it = fi >> 2, mtl = fi & 3;
      const short* g = src + (((size_t)((by * 4 + mtl) * 4 + 0) * 16 + it) * 512 + (size_t)l * 8);
      __builtin_amdgcn_global_load_lds((gas_void*)g, (las_void*)(sm + fi * 512), 16, 0, 0);
    }
#pragma unroll
    for (int c = 0; c < 4; ++c) {
      if (c < 3) {
#pragma unroll
        for (int j = 0; j < 8; ++j) {
          const int fi = w * 8 + j;
          const int it = fi >> 2, mtl = fi & 3;
          const short* g = src + (((size_t)((by * 4 + mtl) * 4 + (c + 1)) * 16 + it) * 512 + (size_t)l * 8);
          __builtin_amdgcn_global_load_lds(
              (gas_void*)g, (las_void*)(sm + ((c + 1) & 1) * 32768 + fi * 512), 16, 0, 0);
        }
        asm volatile("s_waitcnt vmcnt(8)" ::: "memory");  // chunk c landed, c+1 in flight
      } else {
        asm volatile("s_waitcnt vmcnt(0)" ::: "memory");
      }
      __builtin_amdgcn_s_barrier();
      const short* cb = sm + (c & 1) * 32768;
#pragma unroll
      for (int jj = 0; jj < 4; ++jj) {
        const int it = w4 + 4 * jj;
        const short* fb = cb + it * 2048 + l * 8;
        s16x8 a0 = *(const s16x8*)(fb);
        s16x8 a1 = *(const s16x8*)(fb + 512);
        s16x8 a2 = *(const s16x8*)(fb + 1024);
        s16x8 a3 = *(const s16x8*)(fb + 1536);
        const int wb = c * 8 + jj * 2;
        c00 = MF(a0, W[wb], c00); c01 = MF(a0, W[wb + 1], c01);
        c10 = MF(a1, W[wb], c10); c11 = MF(a1, W[wb + 1], c11);
        c20 = MF(a2, W[wb], c20); c21 = MF(a2, W[wb + 1], c21);
        c30 = MF(a3, W[wb], c30); c31 = MF(a3, W[wb + 1], c31);
      }
      __builtin_amdgcn_s_barrier();  // protect buffer (c&1) before chunk c+2 staging
    }

    // ---- partials to LDS: slot s = mtl*2+gi at float ((s*512 + w*64 + l)*4) ----
    {
      float* base = red + (size_t)(w * 64 + l) * 4;
      *(f32x4*)(base + 0 * 2048) = c00;
      *(f32x4*)(base + 1 * 2048) = c01;
      *(f32x4*)(base + 2 * 2048) = c10;
      *(f32x4*)(base + 3 * 2048) = c11;
      *(f32x4*)(base + 4 * 2048) = c20;
      *(f32x4*)(base + 5 * 2048) = c21;
      *(f32x4*)(base + 6 * 2048) = c30;
      *(f32x4*)(base + 7 * 2048) = c31;
    }
    __syncthreads();

    // ---- epilogue: 2 cells/thread ----
#pragma unroll
    for (int cc2 = 0; cc2 < 2; ++cc2) {
      const int mloc = mloc0 + cc2 * 32;
      const int mtl = mloc >> 4, qq = (mloc & 15) >> 2, jj = mloc & 3;
      const int lane = qq * 16 + hc;
      float g4[4];
#pragma unroll
      for (int g = 0; g < 4; ++g) {
        const int s = mtl * 2 + (g & 1);
        const int wv = (g >> 1) * 4;
        float sum = 0.f;
#pragma unroll
        for (int k2 = 0; k2 < 4; ++k2)
          sum += red[(size_t)(s * 512 + (wv + k2) * 64 + lane) * 4 + jj];
        g4[g] = sum;
      }
      const int mg = by * 64 + mloc;
      float gi_ = g4[0] + bsum[chh];
      float gf = g4[1] + bsum[HD + chh];
      float gg = g4[2] + bsum[2 * HD + chh];
      float go = g4[3] + bsum[3 * HD + chh];
      const int idx = mg * HD + chh;
      float cn = sigm(gf) * cbuf[idx] + sigm(gi_) * tanh_f(gg);
      cbuf[idx] = cn;
      float h = sigm(go) * tanh_f(cn);
      short h16 = f2b(h);
      dst[xhf_idx(mg, chh)] = f2b(h > 0.f ? h : 0.f);  // x-half: relu(h)
      dst[xhf_idx(mg, HD + chh)] = h16;                // h-half
      hsC[(size_t)tslot * BD * HD + idx] = h16;
      if (t == TS - 1) { o_h[idx] = h; o_c[idx] = cn; }
    }
    if (++tslot == CH) tslot = 0;

    // ---- per-by grid barrier: xh(t+1) visible to all same-by blocks ----
    grid_bar(ctr + by, 64u * (unsigned)(t + 1));

    // ---- fused out_proj phase every CH steps ----
    if (tslot == 0) {
      if (bx < 2 * CH) {
        const int tloc = bx >> 1, nj = bx & 1;
        const int tglob = t + 1 - CH + tloc;
        const short* hsrc = hsC + (size_t)tloc * BD * HD + (size_t)by * 64 * HD;
        const int amt = w & 3, nfh = w >> 2;
        f32x4 p0 = {}, p1 = {};
#pragma unroll
        for (int cc = 0; cc < 2; ++cc) {
#pragma unroll
          for (int j = 0; j < 8; ++j) {
            const int fi = w * 8 + j;
            const int it = fi >> 2, ml = fi & 3;
            const short* g = hsrc + (size_t)(ml * 16 + r) * HD + (cc * 16 + it) * 32 + q * 8;
            __builtin_amdgcn_global_load_lds((gas_void*)g, (las_void*)(sm + fi * 512), 16, 0, 0);
          }
          asm volatile("s_waitcnt vmcnt(0)" ::: "memory");
          __syncthreads();
#pragma unroll
          for (int itl = 0; itl < 16; ++itl) {
            const short* fb = sm + itl * 2048 + amt * 512 + l * 8;
            s16x8 a = *(const s16x8*)(fb);
            const int kk = (cc * 16 + itl) * 32 + q * 8;
            s16x8 b0 = *(const s16x8*)(outw + (size_t)(nj * 64 + nfh * 32 + r) * HD + kk);
            s16x8 b1 = *(const s16x8*)(outw + (size_t)(nj * 64 + nfh * 32 + 16 + r) * HD + kk);
            p0 = MF(a, b0, p0);
            p1 = MF(a, b1, p1);
          }
          __syncthreads();
        }
#pragma unroll
        for (int f2 = 0; f2 < 2; ++f2) {
          const int col = nj * 64 + nfh * 32 + f2 * 16 + r;
          const float bb = outb[col];
          const f32x4 pa = f2 ? p1 : p0;
#pragma unroll
          for (int j2 = 0; j2 < 4; ++j2) {
            const int brow = by * 64 + amt * 16 + q * 4 + j2;
            dout[((size_t)brow * TS + tglob) * OD + col] = pa[j2] + bb;
          }
        }
      }
      ++pcnt;
      // second barrier: nobody overwrites hsC slot 0 (step t+1) before phase reads end
      grid_bar(ctr + 4 + by, 64u * pcnt);
    }
  }
}

extern "C" void kernel_launch(void* const* d_in, const int* in_sizes, int n_in,
                              void* d_out, int out_size, void* d_ws, size_t ws_size,
                              hipStream_t stream) {
  static const int exp_sizes[26] = {
      131072, 131072, 128, 524288, 1024, 524288, 1024, 131072, 1024,
      4194304, 4194304, 4096, 4096, 131072, 128, 524288, 1024, 1024, 1,
      524288, 1024, 1048576, 1024, 2048, 2, 1};
  if (n_in < 26) return;
  for (int i = 0; i < 26; ++i)
    if (in_sizes[i] != exp_sizes[i]) return;

  const float* enc_out = (const float*)d_in[0];
  const float* enc_hid = (const float*)d_in[1];
  const float* start_tok = (const float*)d_in[2];
  const float* l2h_w = (const float*)d_in[3];
  const float* l2h_b = (const float*)d_in[4];
  const float* l2h2_w = (const float*)d_in[5];
  const float* l2h2_b = (const float*)d_in[6];
  const float* emb_w = (const float*)d_in[7];
  const float* emb_b = (const float*)d_in[8];
  const float* Wih_f = (const float*)d_in[9];
  const float* Whh_f = (const float*)d_in[10];
  const float* bih = (const float*)d_in[11];
  const float* bhh = (const float*)d_in[12];
  const float* outw_f = (const float*)d_in[13];
  const float* outb = (const float*)d_in[14];
  const float* seq_w = (const float*)d_in[15];
  const float* seq_b = (const float*)d_in[16];
  const float* seq2_w = (const float*)d_in[17];
  const float* seq2_b = (const float*)d_in[18];
  const float* mass_w = (const float*)d_in[19];
  const float* mass_b = (const float*)d_in[20];
  const float* mass2_w = (const float*)d_in[21];
  const float* mass2_b = (const float*)d_in[22];
  const float* mass3_w = (const float*)d_in[23];
  const float* mass3_b = (const float*)d_in[24];

  // ---- workspace layout ----
  char* p = (char*)d_ws;
  float* c_buf = (float*)p;  p += (size_t)BD * HD * 4;        // 1 MB
  float* bsum = (float*)p;   p += (size_t)4 * HD * 4;         // 16 KB
  float* n1 = (float*)p;     p += (size_t)BD * HD * 4;        // 1 MB
  short* m1 = (short*)p;     p += (size_t)BD * HD * 2;        // 512 KB
  short* m2 = (short*)p;     p += (size_t)BD * HD * 2;        // 512 KB
  short* xrow = (short*)p;   p += (size_t)HD * 2;             // 2 KB
  short* xhA = (short*)p;    p += (size_t)BD * KC * 2;        // 1 MB
  short* xhB = (short*)p;    p += (size_t)BD * KC * 2;        // 1 MB
  short* Wt = (short*)p;     p += (size_t)4 * HD * KC * 2;    // 16 MB
  short* outw = (short*)p;   p += (size_t)OD * HD * 2;        // 256 KB
  unsigned* ctrs = (unsigned*)p; p += 64;                     // 8 barrier counters
  short* hsC = (short*)p;    // CH * BD * HD bf16
  size_t fixed_bytes = (size_t)(p - (char*)d_ws);
  const size_t step_bytes = (size_t)BD * HD * 2;
  int CH = 0;
  const int cands[7] = {25, 20, 10, 5, 4, 2, 1};
  for (int ci = 0; ci < 7; ++ci) {
    if (fixed_bytes + (size_t)cands[ci] * step_bytes <= ws_size) { CH = cands[ci]; break; }
  }
  if (CH == 0) return;

  float* dout = (float*)d_out;
  float* o_dec = dout;                       // [B][TS][OD]
  float* o_h = dout + (size_t)BD * TS * OD;  // [1][B][HD]
  float* o_c = o_h + (size_t)BD * HD;        // [1][B][HD]
  float* o_num = o_c + (size_t)BD * HD;      // [B][1]
  float* o_mass = o_num + BD;                // [B][2]

  // prep
  wrep_k<<<4096, 256, 0, stream>>>(Wih_f, Whh_f, Wt);
  cvt8_k<<<OD * HD / 2048, 256, 0, stream>>>(outw_f, outw);
  bsum_k<<<16, 256, 0, stream>>>(bih, bhh, bsum);
  x0_k<<<4, 256, 0, stream>>>(start_tok, emb_w, emb_b, xrow);
  bcast_k<<<BD * HD / 256, 256, 0, stream>>>(xrow, xhA);
  zero_ctr_k<<<1, 8, 0, stream>>>(ctrs);

  // heads + initial state
  dim3 fcg(16, 4);
  fc_mfma<LATD, false, 2><<<fcg, 256, 0, stream>>>(enc_hid, l2h_w, l2h_b, xhA, 0, 0);
  fc_mfma<LATD, false, 0><<<fcg, 256, 0, stream>>>(enc_hid, l2h2_w, l2h2_b, c_buf, 0, 0);
  fc_mfma<LATD, false, 0><<<fcg, 256, 0, stream>>>(enc_out, seq_w, seq_b, n1, 0, 0);
  fc_mfma<LATD, false, 1><<<fcg, 256, 0, stream>>>(enc_out, mass_w, mass_b, m1, HD, 0);
  fc_mfma<HD, true, 1><<<fcg, 256, 0, stream>>>(m1, mass2_w, mass2_b, m2, HD, 0);
  num_k<<<64, 256, 0, stream>>>(n1, seq2_w, seq2_b, o_num);
  mass_k<<<64, 256, 0, stream>>>(m2, mass3_w, mass3_b, o_mass);

  // whole LSTM scan + output projection in ONE persistent launch
  lstm_persist<<<dim3(64, 4), 512, 0, stream>>>(
      xhA, xhB, c_buf, Wt, bsum, hsC, outw, outb, o_dec, o_h, o_c, ctrs, CH);
}

// Round 3
// 2614.356 us; speedup vs baseline: 1.2874x; 1.2874x over previous
//
#include <hip/hip_runtime.h>

#define BD 256   // batch
#define HD 1024  // hidden
#define KC 2048  // concatenated K = [x | h]
#define LATD 512 // latent
#define OD 128   // output dim
#define TS 100   // seq_len (fixed by problem)

typedef __attribute__((ext_vector_type(8))) short s16x8;
typedef __attribute__((ext_vector_type(4))) float f32x4;

__device__ __forceinline__ float b2f(short s) {
  return __uint_as_float(((unsigned)(unsigned short)s) << 16);
}
__device__ __forceinline__ short f2b(float f) {
  unsigned u = __float_as_uint(f);
  u += 0x7fff + ((u >> 16) & 1);  // RNE
  return (short)(u >> 16);
}
__device__ __forceinline__ float sigm(float x) { return 1.f / (1.f + __expf(-x)); }
__device__ __forceinline__ float tanh_f(float x) { return 1.f - 2.f / (__expf(2.f * x) + 1.f); }

// xh fragment-major chunk index: m -> (mt=m/16, r=m%16), k -> (kc=k/8, e=k%8)
// kq=kc/64, it=(kc/4)%16, q=kc%4; chunk = ((mt*4+kq)*16+it)*64 + q*16 + r
__device__ __forceinline__ size_t xhf_idx(int m, int k) {
  int kc = k >> 3;
  int kq = kc >> 6, it = (kc >> 2) & 15, q = kc & 3;
  int mt = m >> 4, r = m & 15;
  return ((((size_t)mt * 4 + kq) * 16 + it) * 64 + q * 16 + r) * 8 + (k & 7);
}

// ---------------- one-time prep kernels ----------------

__global__ __launch_bounds__(256) void cvt8_k(const float* __restrict__ in,
                                              short* __restrict__ out) {
  int i = (blockIdx.x * 256 + threadIdx.x) * 8;
  f32x4 a = *(const f32x4*)(in + i), b = *(const f32x4*)(in + i + 4);
  s16x8 o;
#pragma unroll
  for (int e = 0; e < 4; ++e) { o[e] = f2b(a[e]); o[4 + e] = f2b(b[e]); }
  *(s16x8*)(out + i) = o;
}

// Fragment-major weight repack (verified r6):
// chunk i = ((bn*64 + kit)*4 + quad)*16 + lan; bn = g*64+bx; k = kit*32+quad*8
__global__ __launch_bounds__(256) void wrep_k(const float* __restrict__ Wih,
                                              const float* __restrict__ Whh,
                                              short* __restrict__ Wt) {
  int i = blockIdx.x * 256 + threadIdx.x;  // chunk id, < 1048576
  int lan = i & 15, quad = (i >> 4) & 3, kit = (i >> 6) & 63, bn = i >> 12;
  int g = bn >> 6, bx = bn & 63;
  int n = g * HD + bx * 16 + lan;
  int k = kit * 32 + quad * 8;
  const float* src = (k < HD) ? (Wih + (size_t)n * HD + k)
                              : (Whh + (size_t)n * HD + (k - HD));
  f32x4 a = *(const f32x4*)src, b = *(const f32x4*)(src + 4);
  s16x8 o;
#pragma unroll
  for (int e = 0; e < 4; ++e) { o[e] = f2b(a[e]); o[4 + e] = f2b(b[e]); }
  *(s16x8*)(Wt + (size_t)i * 8) = o;
}

__global__ __launch_bounds__(256) void bsum_k(const float* __restrict__ bi,
                                              const float* __restrict__ bh,
                                              float* __restrict__ bs) {
  int i = blockIdx.x * 256 + threadIdx.x;
  bs[i] = bi[i] + bh[i];
}

__global__ __launch_bounds__(256) void x0_k(const float* __restrict__ st,
                                            const float* __restrict__ W,
                                            const float* __restrict__ bias,
                                            short* __restrict__ xrow) {
  int j = blockIdx.x * 256 + threadIdx.x;
  float acc = 0.f;
  for (int k = 0; k < OD; ++k) acc += st[k] * W[j * OD + k];
  acc += bias[j];
  xrow[j] = f2b(acc > 0.f ? acc : 0.f);
}

// x-half init: xhf[m][k] = xrow[k], k<1024
__global__ __launch_bounds__(256) void bcast_k(const short* __restrict__ xrow,
                                               short* __restrict__ xhf) {
  int i = blockIdx.x * 256 + threadIdx.x;  // over BD*HD
  int m = i >> 10, k = i & 1023;
  xhf[xhf_idx(m, k)] = xrow[k];
}

__global__ void zero_ctr_k(unsigned* __restrict__ c) { c[threadIdx.x] = 0u; }

// ---------------- head GEMM: out = lrelu(A @ W^T + b), N=1024, M=256 ----------------
// MODE: 0 = fp32 flat [m*1024+col]; 1 = bf16 flat [m*os+oo+col]; 2 = bf16 xhf h-half
template <int K, bool IN_BF16, int MODE>
__global__ __launch_bounds__(256) void fc_mfma(const void* __restrict__ in_,
                                               const float* __restrict__ W,
                                               const float* __restrict__ bias,
                                               void* __restrict__ out_,
                                               int ostride, int ooff) {
  const int tid = threadIdx.x;
  const int w = tid >> 6, lan = tid & 15, quad = (tid & 63) >> 4;
  const int n0 = blockIdx.x * 64;
  const int m0 = blockIdx.y * 64;
  const int arow = m0 + w * 16 + lan;
  f32x4 acc[4] = {};
  for (int k0 = 0; k0 < K; k0 += 32) {
    const int ka = k0 + quad * 8;
    s16x8 af;
    if (IN_BF16) {
      af = *(const s16x8*)((const short*)in_ + arow * K + ka);
    } else {
      const float* ap = (const float*)in_ + arow * K + ka;
      f32x4 a0 = *(const f32x4*)ap, a1 = *(const f32x4*)(ap + 4);
#pragma unroll
      for (int e = 0; e < 4; ++e) { af[e] = f2b(a0[e]); af[4 + e] = f2b(a1[e]); }
    }
#pragma unroll
    for (int nf = 0; nf < 4; ++nf) {
      const float* bp = W + (n0 + nf * 16 + lan) * K + ka;
      f32x4 b0 = *(const f32x4*)bp, b1 = *(const f32x4*)(bp + 4);
      s16x8 bf;
#pragma unroll
      for (int e = 0; e < 4; ++e) { bf[e] = f2b(b0[e]); bf[4 + e] = f2b(b1[e]); }
      acc[nf] = __builtin_amdgcn_mfma_f32_16x16x32_bf16(af, bf, acc[nf], 0, 0, 0);
    }
  }
#pragma unroll
  for (int nf = 0; nf < 4; ++nf) {
    int col = n0 + nf * 16 + lan;
    float bb = bias[col];
#pragma unroll
    for (int j = 0; j < 4; ++j) {
      int m = m0 + w * 16 + quad * 4 + j;
      float v = acc[nf][j] + bb;
      v = v > 0.f ? v : 0.01f * v;
      if (MODE == 0)
        ((float*)out_)[m * 1024 + col] = v;
      else if (MODE == 1)
        ((short*)out_)[m * ostride + ooff + col] = f2b(v);
      else
        ((short*)out_)[xhf_idx(m, HD + col)] = f2b(v);
    }
  }
}

__global__ __launch_bounds__(256) void num_k(const float* __restrict__ n1,
                                             const float* __restrict__ w2,
                                             const float* __restrict__ b2,
                                             float* __restrict__ out) {
  int l = threadIdx.x & 63, w = threadIdx.x >> 6;
  int m = blockIdx.x * 4 + w;
  const float* r = n1 + m * HD + l * 16;
  const float* wv = w2 + l * 16;
  float acc = 0.f;
#pragma unroll
  for (int c = 0; c < 4; ++c) {
    f32x4 a = *(const f32x4*)(r + c * 4), b = *(const f32x4*)(wv + c * 4);
#pragma unroll
    for (int e = 0; e < 4; ++e) acc += a[e] * b[e];
  }
  for (int off = 32; off; off >>= 1) acc += __shfl_down(acc, off);
  if (l == 0) {
    float v = acc + b2[0];
    out[m] = v > 0.f ? v : 0.f;
  }
}

__global__ __launch_bounds__(256) void mass_k(const short* __restrict__ m2,
                                              const float* __restrict__ w3,
                                              const float* __restrict__ b3,
                                              float* __restrict__ out) {
  int l = threadIdx.x & 63, w = threadIdx.x >> 6;
  int m = blockIdx.x * 4 + w;
  const short* r = m2 + m * HD + l * 16;
  s16x8 v0 = *(const s16x8*)r, v1 = *(const s16x8*)(r + 8);
  float z0 = 0.f, z1 = 0.f;
#pragma unroll
  for (int e = 0; e < 8; ++e) {
    float a = b2f(v0[e]), b = b2f(v1[e]);
    z0 += a * w3[l * 16 + e] + b * w3[l * 16 + 8 + e];
    z1 += a * w3[HD + l * 16 + e] + b * w3[HD + l * 16 + 8 + e];
  }
  for (int off = 32; off; off >>= 1) {
    z0 += __shfl_down(z0, off);
    z1 += __shfl_down(z1, off);
  }
  if (l == 0) {
    z0 += b3[0]; z1 += b3[1];
    float mx = fmaxf(z0, z1);
    float e0 = __expf(z0 - mx), e1 = __expf(z1 - mx);
    float s = e0 + e1;
    out[m * 2] = e0 / s;
    out[m * 2 + 1] = e1 / s;
  }
}

// ---------------- persistent LSTM kernel ----------------
// Grid (64,4) = 256 blocks, 512 threads (8 waves). One block per CU, enforced by
// 128 KB static LDS. All gate weights in VGPRs (128/thread). Activation tile
// streams via the R0-proven 2x64KB double-buffered global_load_lds (vmcnt(8)).
// Cross-step sync: ZERO-RMW barrier — each block stores its own slot (no atomic
// contention); block bx==0's wave 0 polls 64 slots lane-parallel and releases a
// flag; others poll the flag with relaxed agent-scope loads. __threadfence pair
// provides cross-XCD data visibility (validated R0).

#define MF(a, b, c) __builtin_amdgcn_mfma_f32_16x16x32_bf16(a, b, c, 0, 0, 0)

typedef __attribute__((address_space(1))) const void gas_void;
typedef __attribute__((address_space(3))) void las_void;

// slots: 64 words (one per block); flag: separate cache line.
__device__ __forceinline__ void grid_bar(unsigned* slots, unsigned* flag,
                                         unsigned epoch, int bx) {
  __syncthreads();  // compiler drains vmcnt/lgkmcnt before s_barrier: stores in L2
  const int tid = threadIdx.x;
  if (bx == 0) {
    if (tid < 64) {  // wave 0 = poller
      if (tid == 0) {
        __threadfence();  // release: own stores visible device-wide
        __hip_atomic_store(slots, epoch, __ATOMIC_RELAXED, __HIP_MEMORY_SCOPE_AGENT);
      }
      while (!__all(__hip_atomic_load(slots + tid, __ATOMIC_RELAXED,
                                      __HIP_MEMORY_SCOPE_AGENT) >= epoch))
        __builtin_amdgcn_s_sleep(2);
      if (tid == 0) {
        __threadfence();  // acquire for this block + order flag after sweep
        __hip_atomic_store(flag, epoch, __ATOMIC_RELAXED, __HIP_MEMORY_SCOPE_AGENT);
      }
    }
  } else {
    if (tid == 0) {
      __threadfence();  // release: own stores visible device-wide
      __hip_atomic_store(slots + bx, epoch, __ATOMIC_RELAXED, __HIP_MEMORY_SCOPE_AGENT);
      while (__hip_atomic_load(flag, __ATOMIC_RELAXED, __HIP_MEMORY_SCOPE_AGENT) < epoch)
        __builtin_amdgcn_s_sleep(2);
      __threadfence();  // acquire: drop stale L1/L2 before reading peers' xh
    }
  }
  __syncthreads();
}

__global__ __launch_bounds__(512, 2) void lstm_persist(
    short* __restrict__ xhA, short* __restrict__ xhB, const float* __restrict__ cbuf,
    const short* __restrict__ Wt, const float* __restrict__ bsum,
    short* __restrict__ hsC, const short* __restrict__ outw,
    const float* __restrict__ outb, float* __restrict__ dout,
    float* __restrict__ o_h, float* __restrict__ o_c,
    unsigned* ctr, int CH) {
  __shared__ __align__(16) short sm[65536];  // 128 KB: 2 x 64 KB chunk dbuf / red / phase

  const int tid = threadIdx.x;
  const int w = tid >> 6, l = tid & 63;
  const int w4 = w & 3, gp = w >> 2;     // wave = (K-interleave, gate-pair)
  const int bx = blockIdx.x, by = blockIdx.y;
  const int q = l >> 4, r = l & 15;

  // ---- one-time weight preload: 32 frags = 128 VGPR/thread ----
  // frag (c,jj,gi): gate g = gp*2+gi, kit = c*16 + w4 + 4*jj
  s16x8 W[32];
#pragma unroll
  for (int c = 0; c < 4; ++c)
#pragma unroll
    for (int jj = 0; jj < 4; ++jj)
#pragma unroll
      for (int gi = 0; gi < 2; ++gi) {
        const int g = gp * 2 + gi;
        const int kit = c * 16 + w4 + 4 * jj;
        const size_t bn = (size_t)(g * 64 + bx);
        W[c * 8 + jj * 2 + gi] =
            *(const s16x8*)(Wt + ((bn * 64 + kit) * 64 + l) * 8);
      }

  // ---- per-thread epilogue constants (cells are t-invariant) ----
  const int mloc0 = tid >> 4, hc = tid & 15;
  const int chh = bx * 16 + hc;
  const float bs0 = bsum[chh], bs1 = bsum[HD + chh];
  const float bs2 = bsum[2 * HD + chh], bs3 = bsum[3 * HD + chh];
  int idxA[2];
  size_t xIdx[2], hIdx[2];
  float creg[2];
#pragma unroll
  for (int cc2 = 0; cc2 < 2; ++cc2) {
    const int mg = by * 64 + mloc0 + cc2 * 32;
    idxA[cc2] = mg * HD + chh;
    xIdx[cc2] = xhf_idx(mg, chh);
    hIdx[cc2] = xhf_idx(mg, HD + chh);
    creg[cc2] = cbuf[idxA[cc2]];  // c-state lives in registers for all 100 steps
  }

  float* red = (float*)sm;
  unsigned* cbase = ctr + by * 256;            // 1 KB per by-group
  unsigned* s1 = cbase;                        // 64 arrival slots (bar1)
  unsigned* f1 = cbase + 80;                   // release flag (own line)
  unsigned* s2 = cbase + 128;                  // 64 arrival slots (bar2)
  unsigned* f2g = cbase + 208;                 // release flag (own line)
  int tslot = 0;
  unsigned pcnt = 0;

  for (int t = 0; t < TS; ++t) {
    const short* src = (t & 1) ? xhB : xhA;
    short* dst = (t & 1) ? xhA : xhB;

    f32x4 c00 = {}, c01 = {}, c10 = {}, c11 = {};
    f32x4 c20 = {}, c21 = {}, c30 = {}, c31 = {};

    // stage chunk 0 (8 frags/wave, 1 KB each) into buffer 0
#pragma unroll
    for (int j = 0; j < 8; ++j) {
      const int fi = w * 8 + j;
      const int it = fi >> 2, mtl = fi & 3;
      const short* g = src + (((size_t)((by * 4 + mtl) * 4 + 0) * 16 + it) * 512 + (size_t)l * 8);
      __builtin_amdgcn_global_load_lds((gas_void*)g, (las_void*)(sm + fi * 512), 16, 0, 0);
    }
#pragma unroll
    for (int c = 0; c < 4; ++c) {
      if (c < 3) {
#pragma unroll
        for (int j = 0; j < 8; ++j) {
          const int fi = w * 8 + j;
          const int it = fi >> 2, mtl = fi & 3;
          const short* g = src + (((size_t)((by * 4 + mtl) * 4 + (c + 1)) * 16 + it) * 512 + (size_t)l * 8);
          __builtin_amdgcn_global_load_lds(
              (gas_void*)g, (las_void*)(sm + ((c + 1) & 1) * 32768 + fi * 512), 16, 0, 0);
        }
        asm volatile("s_waitcnt vmcnt(8)" ::: "memory");  // chunk c landed, c+1 in flight
      } else {
        asm volatile("s_waitcnt vmcnt(0)" ::: "memory");
      }
      __builtin_amdgcn_s_barrier();
      const short* cb = sm + (c & 1) * 32768;
#pragma unroll
      for (int jj = 0; jj < 4; ++jj) {
        const int it = w4 + 4 * jj;
        const short* fb = cb + it * 2048 + l * 8;
        s16x8 a0 = *(const s16x8*)(fb);
        s16x8 a1 = *(const s16x8*)(fb + 512);
        s16x8 a2 = *(const s16x8*)(fb + 1024);
        s16x8 a3 = *(const s16x8*)(fb + 1536);
        const int wb = c * 8 + jj * 2;
        c00 = MF(a0, W[wb], c00); c01 = MF(a0, W[wb + 1], c01);
        c10 = MF(a1, W[wb], c10); c11 = MF(a1, W[wb + 1], c11);
        c20 = MF(a2, W[wb], c20); c21 = MF(a2, W[wb + 1], c21);
        c30 = MF(a3, W[wb], c30); c31 = MF(a3, W[wb + 1], c31);
      }
      __builtin_amdgcn_s_barrier();  // protect buffer (c&1) before chunk c+2 staging
    }

    // ---- partials to LDS: slot s = mtl*2+gi at float ((s*512 + w*64 + l)*4) ----
    {
      float* base = red + (size_t)(w * 64 + l) * 4;
      *(f32x4*)(base + 0 * 2048) = c00;
      *(f32x4*)(base + 1 * 2048) = c01;
      *(f32x4*)(base + 2 * 2048) = c10;
      *(f32x4*)(base + 3 * 2048) = c11;
      *(f32x4*)(base + 4 * 2048) = c20;
      *(f32x4*)(base + 5 * 2048) = c21;
      *(f32x4*)(base + 6 * 2048) = c30;
      *(f32x4*)(base + 7 * 2048) = c31;
    }
    __syncthreads();

    // ---- epilogue: 2 cells/thread, c-state in registers ----
#pragma unroll
    for (int cc2 = 0; cc2 < 2; ++cc2) {
      const int mloc = mloc0 + cc2 * 32;
      const int mtl = mloc >> 4, qq = (mloc & 15) >> 2, jj = mloc & 3;
      const int lane = qq * 16 + hc;
      float g4[4];
#pragma unroll
      for (int g = 0; g < 4; ++g) {
        const int s = mtl * 2 + (g & 1);
        const int wv = (g >> 1) * 4;
        float sum = 0.f;
#pragma unroll
        for (int k2 = 0; k2 < 4; ++k2)
          sum += red[(size_t)(s * 512 + (wv + k2) * 64 + lane) * 4 + jj];
        g4[g] = sum;
      }
      float gi_ = g4[0] + bs0;
      float gf = g4[1] + bs1;
      float gg = g4[2] + bs2;
      float go = g4[3] + bs3;
      float cn = sigm(gf) * creg[cc2] + sigm(gi_) * tanh_f(gg);
      creg[cc2] = cn;
      float h = sigm(go) * tanh_f(cn);
      short h16 = f2b(h);
      dst[xIdx[cc2]] = f2b(h > 0.f ? h : 0.f);  // x-half: relu(h)
      dst[hIdx[cc2]] = h16;                     // h-half
      hsC[(size_t)tslot * BD * HD + idxA[cc2]] = h16;
      if (t == TS - 1) { o_h[idxA[cc2]] = h; o_c[idxA[cc2]] = cn; }
    }
    if (++tslot == CH) tslot = 0;

    // ---- per-by grid barrier: xh(t+1) visible to all same-by blocks ----
    grid_bar(s1, f1, (unsigned)(t + 1), bx);

    // ---- fused out_proj phase every CH steps ----
    if (tslot == 0) {
      if (bx < 2 * CH) {
        const int tloc = bx >> 1, nj = bx & 1;
        const int tglob = t + 1 - CH + tloc;
        const short* hsrc = hsC + (size_t)tloc * BD * HD + (size_t)by * 64 * HD;
        const int amt = w & 3, nfh = w >> 2;
        f32x4 p0 = {}, p1 = {};
#pragma unroll
        for (int cc = 0; cc < 2; ++cc) {
#pragma unroll
          for (int j = 0; j < 8; ++j) {
            const int fi = w * 8 + j;
            const int it = fi >> 2, ml = fi & 3;
            const short* g = hsrc + (size_t)(ml * 16 + r) * HD + (cc * 16 + it) * 32 + q * 8;
            __builtin_amdgcn_global_load_lds((gas_void*)g, (las_void*)(sm + fi * 512), 16, 0, 0);
          }
          asm volatile("s_waitcnt vmcnt(0)" ::: "memory");
          __syncthreads();
#pragma unroll
          for (int itl = 0; itl < 16; ++itl) {
            const short* fb = sm + itl * 2048 + amt * 512 + l * 8;
            s16x8 a = *(const s16x8*)(fb);
            const int kk = (cc * 16 + itl) * 32 + q * 8;
            s16x8 b0 = *(const s16x8*)(outw + (size_t)(nj * 64 + nfh * 32 + r) * HD + kk);
            s16x8 b1 = *(const s16x8*)(outw + (size_t)(nj * 64 + nfh * 32 + 16 + r) * HD + kk);
            p0 = MF(a, b0, p0);
            p1 = MF(a, b1, p1);
          }
          __syncthreads();
        }
#pragma unroll
        for (int f2 = 0; f2 < 2; ++f2) {
          const int col = nj * 64 + nfh * 32 + f2 * 16 + r;
          const float bb = outb[col];
          const f32x4 pa = f2 ? p1 : p0;
#pragma unroll
          for (int j2 = 0; j2 < 4; ++j2) {
            const int brow = by * 64 + amt * 16 + q * 4 + j2;
            dout[((size_t)brow * TS + tglob) * OD + col] = pa[j2] + bb;
          }
        }
      }
      ++pcnt;
      // nobody overwrites hsC slot 0 before this by-group's phase reads finish
      grid_bar(s2, f2g, pcnt, bx);
    }
  }
}

extern "C" void kernel_launch(void* const* d_in, const int* in_sizes, int n_in,
                              void* d_out, int out_size, void* d_ws, size_t ws_size,
                              hipStream_t stream) {
  static const int exp_sizes[26] = {
      131072, 131072, 128, 524288, 1024, 524288, 1024, 131072, 1024,
      4194304, 4194304, 4096, 4096, 131072, 128, 524288, 1024, 1024, 1,
      524288, 1024, 1048576, 1024, 2048, 2, 1};
  if (n_in < 26) return;
  for (int i = 0; i < 26; ++i)
    if (in_sizes[i] != exp_sizes[i]) return;

  const float* enc_out = (const float*)d_in[0];
  const float* enc_hid = (const float*)d_in[1];
  const float* start_tok = (const float*)d_in[2];
  const float* l2h_w = (const float*)d_in[3];
  const float* l2h_b = (const float*)d_in[4];
  const float* l2h2_w = (const float*)d_in[5];
  const float* l2h2_b = (const float*)d_in[6];
  const float* emb_w = (const float*)d_in[7];
  const float* emb_b = (const float*)d_in[8];
  const float* Wih_f = (const float*)d_in[9];
  const float* Whh_f = (const float*)d_in[10];
  const float* bih = (const float*)d_in[11];
  const float* bhh = (const float*)d_in[12];
  const float* outw_f = (const float*)d_in[13];
  const float* outb = (const float*)d_in[14];
  const float* seq_w = (const float*)d_in[15];
  const float* seq_b = (const float*)d_in[16];
  const float* seq2_w = (const float*)d_in[17];
  const float* seq2_b = (const float*)d_in[18];
  const float* mass_w = (const float*)d_in[19];
  const float* mass_b = (const float*)d_in[20];
  const float* mass2_w = (const float*)d_in[21];
  const float* mass2_b = (const float*)d_in[22];
  const float* mass3_w = (const float*)d_in[23];
  const float* mass3_b = (const float*)d_in[24];

  // ---- workspace layout ----
  char* p = (char*)d_ws;
  float* c_buf = (float*)p;  p += (size_t)BD * HD * 4;        // 1 MB
  float* bsum = (float*)p;   p += (size_t)4 * HD * 4;         // 16 KB
  float* n1 = (float*)p;     p += (size_t)BD * HD * 4;        // 1 MB
  short* m1 = (short*)p;     p += (size_t)BD * HD * 2;        // 512 KB
  short* m2 = (short*)p;     p += (size_t)BD * HD * 2;        // 512 KB
  short* xrow = (short*)p;   p += (size_t)HD * 2;             // 2 KB
  short* xhA = (short*)p;    p += (size_t)BD * KC * 2;        // 1 MB
  short* xhB = (short*)p;    p += (size_t)BD * KC * 2;        // 1 MB
  short* Wt = (short*)p;     p += (size_t)4 * HD * KC * 2;    // 16 MB
  short* outw = (short*)p;   p += (size_t)OD * HD * 2;        // 256 KB
  unsigned* ctrs = (unsigned*)p; p += 4096;                   // 4 by x 1 KB
  short* hsC = (short*)p;    // CH * BD * HD bf16
  size_t fixed_bytes = (size_t)(p - (char*)d_ws);
  const size_t step_bytes = (size_t)BD * HD * 2;
  int CH = 0;
  const int cands[7] = {25, 20, 10, 5, 4, 2, 1};
  for (int ci = 0; ci < 7; ++ci) {
    if (fixed_bytes + (size_t)cands[ci] * step_bytes <= ws_size) { CH = cands[ci]; break; }
  }
  if (CH == 0) return;

  float* dout = (float*)d_out;
  float* o_dec = dout;                       // [B][TS][OD]
  float* o_h = dout + (size_t)BD * TS * OD;  // [1][B][HD]
  float* o_c = o_h + (size_t)BD * HD;        // [1][B][HD]
  float* o_num = o_c + (size_t)BD * HD;      // [B][1]
  float* o_mass = o_num + BD;                // [B][2]

  // prep
  wrep_k<<<4096, 256, 0, stream>>>(Wih_f, Whh_f, Wt);
  cvt8_k<<<OD * HD / 2048, 256, 0, stream>>>(outw_f, outw);
  bsum_k<<<16, 256, 0, stream>>>(bih, bhh, bsum);
  x0_k<<<4, 256, 0, stream>>>(start_tok, emb_w, emb_b, xrow);
  bcast_k<<<BD * HD / 256, 256, 0, stream>>>(xrow, xhA);
  zero_ctr_k<<<1, 1024, 0, stream>>>(ctrs);

  // heads + initial state
  dim3 fcg(16, 4);
  fc_mfma<LATD, false, 2><<<fcg, 256, 0, stream>>>(enc_hid, l2h_w, l2h_b, xhA, 0, 0);
  fc_mfma<LATD, false, 0><<<fcg, 256, 0, stream>>>(enc_hid, l2h2_w, l2h2_b, c_buf, 0, 0);
  fc_mfma<LATD, false, 0><<<fcg, 256, 0, stream>>>(enc_out, seq_w, seq_b, n1, 0, 0);
  fc_mfma<LATD, false, 1><<<fcg, 256, 0, stream>>>(enc_out, mass_w, mass_b, m1, HD, 0);
  fc_mfma<HD, true, 1><<<fcg, 256, 0, stream>>>(m1, mass2_w, mass2_b, m2, HD, 0);
  num_k<<<64, 256, 0, stream>>>(n1, seq2_w, seq2_b, o_num);
  mass_k<<<64, 256, 0, stream>>>(m2, mass3_w, mass3_b, o_mass);

  // whole LSTM scan + output projection in ONE persistent launch
  lstm_persist<<<dim3(64, 4), 512, 0, stream>>>(
      xhA, xhB, c_buf, Wt, bsum, hsC, outw, outb, o_dec, o_h, o_c, ctrs, CH);
}

// Round 4
// 1410.193 us; speedup vs baseline: 2.3868x; 1.8539x over previous
//
#include <hip/hip_runtime.h>

#define BD 256   // batch
#define HD 1024  // hidden
#define KC 2048  // concatenated K = [x | h]
#define LATD 512 // latent
#define OD 128   // output dim
#define TS 100   // seq_len (fixed by problem)

typedef __attribute__((ext_vector_type(8))) short s16x8;
typedef __attribute__((ext_vector_type(4))) float f32x4;

__device__ __forceinline__ float b2f(short s) {
  return __uint_as_float(((unsigned)(unsigned short)s) << 16);
}
__device__ __forceinline__ short f2b(float f) {
  unsigned u = __float_as_uint(f);
  u += 0x7fff + ((u >> 16) & 1);  // RNE
  return (short)(u >> 16);
}
__device__ __forceinline__ float sigm(float x) { return 1.f / (1.f + __expf(-x)); }
__device__ __forceinline__ float tanh_f(float x) { return 1.f - 2.f / (__expf(2.f * x) + 1.f); }

// h-only fragment-major index over kh in [0,1024):
// kc=kh/8, q2=kc/64 (h-quarter), it=(kc/4)%16, qq=kc%4; mt=m/16, r=m%16
// frag (mt,q2,it) base = (mt*32 + q2*16 + it)*512 shorts; lane entry qq*16+r at *8
__device__ __forceinline__ size_t hf_idx(int m, int kh) {
  int kc = kh >> 3;
  int q2 = kc >> 6, it = (kc >> 2) & 15, qq = kc & 3;
  int mt = m >> 4, r = m & 15;
  return (((size_t)(mt * 32 + q2 * 16 + it)) * 64 + qq * 16 + r) * 8 + (kh & 7);
}

// relu on bf16 == signed 16-bit max(s,0) (exact; -0 -> +0)
__device__ __forceinline__ s16x8 relu8(s16x8 v) {
  s16x8 o;
#pragma unroll
  for (int e = 0; e < 8; ++e) o[e] = v[e] > 0 ? v[e] : (short)0;
  return o;
}

// ---------------- one-time prep kernels ----------------

__global__ __launch_bounds__(256) void cvt8_k(const float* __restrict__ in,
                                              short* __restrict__ out) {
  int i = (blockIdx.x * 256 + threadIdx.x) * 8;
  f32x4 a = *(const f32x4*)(in + i), b = *(const f32x4*)(in + i + 4);
  s16x8 o;
#pragma unroll
  for (int e = 0; e < 4; ++e) { o[e] = f2b(a[e]); o[4 + e] = f2b(b[e]); }
  *(s16x8*)(out + i) = o;
}

// Fragment-major weight repack (verified r6):
// chunk i = ((bn*64 + kit)*4 + quad)*16 + lan; bn = g*64+bx; k = kit*32+quad*8
__global__ __launch_bounds__(256) void wrep_k(const float* __restrict__ Wih,
                                              const float* __restrict__ Whh,
                                              short* __restrict__ Wt) {
  int i = blockIdx.x * 256 + threadIdx.x;  // chunk id, < 1048576
  int lan = i & 15, quad = (i >> 4) & 3, kit = (i >> 6) & 63, bn = i >> 12;
  int g = bn >> 6, bx = bn & 63;
  int n = g * HD + bx * 16 + lan;
  int k = kit * 32 + quad * 8;
  const float* src = (k < HD) ? (Wih + (size_t)n * HD + k)
                              : (Whh + (size_t)n * HD + (k - HD));
  f32x4 a = *(const f32x4*)src, b = *(const f32x4*)(src + 4);
  s16x8 o;
#pragma unroll
  for (int e = 0; e < 4; ++e) { o[e] = f2b(a[e]); o[4 + e] = f2b(b[e]); }
  *(s16x8*)(Wt + (size_t)i * 8) = o;
}

__global__ __launch_bounds__(256) void bsum_k(const float* __restrict__ bi,
                                              const float* __restrict__ bh,
                                              float* __restrict__ bs) {
  int i = blockIdx.x * 256 + threadIdx.x;
  bs[i] = bi[i] + bh[i];
}

__global__ __launch_bounds__(256) void x0_k(const float* __restrict__ st,
                                            const float* __restrict__ W,
                                            const float* __restrict__ bias,
                                            short* __restrict__ xrow) {
  int j = blockIdx.x * 256 + threadIdx.x;
  float acc = 0.f;
  for (int k = 0; k < OD; ++k) acc += st[k] * W[j * OD + k];
  acc += bias[j];
  xrow[j] = f2b(acc > 0.f ? acc : 0.f);
}

// xg[j] = sum_k relu(x0)[k] * Wih[j][k]  (step-0 x-contribution, batch-invariant)
__global__ __launch_bounds__(256) void xg_k(const short* __restrict__ xrow,
                                            const float* __restrict__ Wih,
                                            float* __restrict__ xg) {
  int l = threadIdx.x & 63, w = threadIdx.x >> 6;
  int j = blockIdx.x * 4 + w;  // 1024 blocks -> j < 4096
  const float* row = Wih + (size_t)j * HD + l * 16;
  float acc = 0.f;
#pragma unroll
  for (int c = 0; c < 16; ++c) acc += b2f(xrow[l * 16 + c]) * row[c];
  for (int off = 32; off; off >>= 1) acc += __shfl_down(acc, off);
  if (l == 0) xg[j] = acc;
}

__global__ void zero_ctr_k(unsigned* __restrict__ c) { c[threadIdx.x] = 0u; }

// ---------------- head GEMM: out = lrelu(A @ W^T + b), N=1024, M=256 ----------------
// MODE: 0 = fp32 flat [m*1024+col]; 1 = bf16 flat [m*os+oo+col]; 2 = bf16 hf layout
template <int K, bool IN_BF16, int MODE>
__global__ __launch_bounds__(256) void fc_mfma(const void* __restrict__ in_,
                                               const float* __restrict__ W,
                                               const float* __restrict__ bias,
                                               void* __restrict__ out_,
                                               int ostride, int ooff) {
  const int tid = threadIdx.x;
  const int w = tid >> 6, lan = tid & 15, quad = (tid & 63) >> 4;
  const int n0 = blockIdx.x * 64;
  const int m0 = blockIdx.y * 64;
  const int arow = m0 + w * 16 + lan;
  f32x4 acc[4] = {};
  for (int k0 = 0; k0 < K; k0 += 32) {
    const int ka = k0 + quad * 8;
    s16x8 af;
    if (IN_BF16) {
      af = *(const s16x8*)((const short*)in_ + arow * K + ka);
    } else {
      const float* ap = (const float*)in_ + arow * K + ka;
      f32x4 a0 = *(const f32x4*)ap, a1 = *(const f32x4*)(ap + 4);
#pragma unroll
      for (int e = 0; e < 4; ++e) { af[e] = f2b(a0[e]); af[4 + e] = f2b(a1[e]); }
    }
#pragma unroll
    for (int nf = 0; nf < 4; ++nf) {
      const float* bp = W + (n0 + nf * 16 + lan) * K + ka;
      f32x4 b0 = *(const f32x4*)bp, b1 = *(const f32x4*)(bp + 4);
      s16x8 bf;
#pragma unroll
      for (int e = 0; e < 4; ++e) { bf[e] = f2b(b0[e]); bf[4 + e] = f2b(b1[e]); }
      acc[nf] = __builtin_amdgcn_mfma_f32_16x16x32_bf16(af, bf, acc[nf], 0, 0, 0);
    }
  }
#pragma unroll
  for (int nf = 0; nf < 4; ++nf) {
    int col = n0 + nf * 16 + lan;
    float bb = bias[col];
#pragma unroll
    for (int j = 0; j < 4; ++j) {
      int m = m0 + w * 16 + quad * 4 + j;
      float v = acc[nf][j] + bb;
      v = v > 0.f ? v : 0.01f * v;
      if (MODE == 0)
        ((float*)out_)[m * 1024 + col] = v;
      else if (MODE == 1)
        ((short*)out_)[m * ostride + ooff + col] = f2b(v);
      else
        ((short*)out_)[hf_idx(m, col)] = f2b(v);
    }
  }
}

__global__ __launch_bounds__(256) void num_k(const float* __restrict__ n1,
                                             const float* __restrict__ w2,
                                             const float* __restrict__ b2,
                                             float* __restrict__ out) {
  int l = threadIdx.x & 63, w = threadIdx.x >> 6;
  int m = blockIdx.x * 4 + w;
  const float* r = n1 + m * HD + l * 16;
  const float* wv = w2 + l * 16;
  float acc = 0.f;
#pragma unroll
  for (int c = 0; c < 4; ++c) {
    f32x4 a = *(const f32x4*)(r + c * 4), b = *(const f32x4*)(wv + c * 4);
#pragma unroll
    for (int e = 0; e < 4; ++e) acc += a[e] * b[e];
  }
  for (int off = 32; off; off >>= 1) acc += __shfl_down(acc, off);
  if (l == 0) {
    float v = acc + b2[0];
    out[m] = v > 0.f ? v : 0.f;
  }
}

__global__ __launch_bounds__(256) void mass_k(const short* __restrict__ m2,
                                              const float* __restrict__ w3,
                                              const float* __restrict__ b3,
                                              float* __restrict__ out) {
  int l = threadIdx.x & 63, w = threadIdx.x >> 6;
  int m = blockIdx.x * 4 + w;
  const short* r = m2 + m * HD + l * 16;
  s16x8 v0 = *(const s16x8*)r, v1 = *(const s16x8*)(r + 8);
  float z0 = 0.f, z1 = 0.f;
#pragma unroll
  for (int e = 0; e < 8; ++e) {
    float a = b2f(v0[e]), b = b2f(v1[e]);
    z0 += a * w3[l * 16 + e] + b * w3[l * 16 + 8 + e];
    z1 += a * w3[HD + l * 16 + e] + b * w3[HD + l * 16 + 8 + e];
  }
  for (int off = 32; off; off >>= 1) {
    z0 += __shfl_down(z0, off);
    z1 += __shfl_down(z1, off);
  }
  if (l == 0) {
    z0 += b3[0]; z1 += b3[1];
    float mx = fmaxf(z0, z1);
    float e0 = __expf(z0 - mx), e1 = __expf(z1 - mx);
    float s = e0 + e1;
    out[m * 2] = e0 / s;
    out[m * 2 + 1] = e1 / s;
  }
}

// ---------------- persistent LSTM kernel ----------------
// Grid (64,4), 512 threads (8 waves), one block/CU (128 KB LDS forces it).
// Weights truly pinned in VGPRs (asm pin, 128 VGPR/thread). Per step only h
// (128 KB/block) is staged, via sc0|sc1 (coherence-point) global_load_lds;
// h stores are agent-scope relaxed (write-through). NO L2 fences anywhere.
// Wave w4 owns K-quarter w4 of the 2048-K GEMM: w4<2 -> x-half (relu in reg),
// w4>=2 -> h-half. t==0: x-waves skip, precomputed xg added in epilogue.

#define MF(a, b, c) __builtin_amdgcn_mfma_f32_16x16x32_bf16(a, b, c, 0, 0, 0)

typedef __attribute__((address_space(1))) const void gas_void;
typedef __attribute__((address_space(3))) void las_void;

// single-hop barrier: one agent store per block; wave 0 polls all 64 slots.
__device__ __forceinline__ void grid_bar(unsigned* slots, unsigned epoch, int bx) {
  asm volatile("s_waitcnt vmcnt(0)" ::: "memory");  // all sc1 stores acked at L3
  __syncthreads();
  if (threadIdx.x == 0)
    __hip_atomic_store(slots + bx, epoch, __ATOMIC_RELAXED, __HIP_MEMORY_SCOPE_AGENT);
  if (threadIdx.x < 64) {
    while (!__all(__hip_atomic_load(slots + (int)threadIdx.x, __ATOMIC_RELAXED,
                                    __HIP_MEMORY_SCOPE_AGENT) >= epoch))
      __builtin_amdgcn_s_sleep(1);
  }
  __syncthreads();
}

__global__ __launch_bounds__(512, 2) void lstm_persist(
    short* __restrict__ hA, short* __restrict__ hB, const float* __restrict__ cbuf,
    const short* __restrict__ Wt, const float* __restrict__ bsum,
    const float* __restrict__ xg, short* __restrict__ hsC,
    const short* __restrict__ outw, const float* __restrict__ outb,
    float* __restrict__ dout, float* __restrict__ o_h, float* __restrict__ o_c,
    unsigned* ctr, int CH) {
  __shared__ __align__(16) short sm[65536];  // 2 x 64 KB h-quarter buffers; red reuses [0,64K)

  const int tid = threadIdx.x;
  const int w = tid >> 6, l = tid & 63;
  const int w4 = w & 3, gp = w >> 2;   // wave = (K-quarter, gate-pair)
  const int bx = blockIdx.x, by = blockIdx.y;
  const int q = l >> 4, r = l & 15;
  const int q2 = w4 & 1;               // h-quarter this wave consumes
  const int sr = (w4 >> 1) + 2 * gp;   // stager rank within quarter [0,4)

  // ---- one-time weight preload: kq = w4, 32 frags = 128 VGPR/thread ----
  s16x8 W[32];
#pragma unroll
  for (int it = 0; it < 16; ++it)
#pragma unroll
    for (int gi = 0; gi < 2; ++gi) {
      const int g = gp * 2 + gi;
      W[it * 2 + gi] =
          *(const s16x8*)(Wt + (((size_t)(g * 64 + bx) * 64 + w4 * 16 + it) * 64 + l) * 8);
    }
  // pin: opaque to the register allocator -> no remat/re-stream from L2
#pragma unroll
  for (int i = 0; i < 32; ++i) asm volatile("" : "+v"(W[i]));

  // ---- per-thread epilogue constants ----
  const int mloc0 = tid >> 4, hc = tid & 15;
  const int chh = bx * 16 + hc;
  const float bs0 = bsum[chh], bs1 = bsum[HD + chh];
  const float bs2 = bsum[2 * HD + chh], bs3 = bsum[3 * HD + chh];
  const float xg0 = xg[chh], xg1 = xg[HD + chh];
  const float xg2 = xg[2 * HD + chh], xg3 = xg[3 * HD + chh];
  int idxA[2];
  size_t hIdx[2];
  float creg[2];
#pragma unroll
  for (int cc2 = 0; cc2 < 2; ++cc2) {
    const int mg = by * 64 + mloc0 + cc2 * 32;
    idxA[cc2] = mg * HD + chh;
    hIdx[cc2] = hf_idx(mg, chh);
    creg[cc2] = cbuf[idxA[cc2]];  // c-state in registers for all 100 steps
  }

  float* red = (float*)sm;
  unsigned* s1 = ctr + by * 128;
  unsigned* s2 = s1 + 64;
  int tslot = 0;
  unsigned pcnt = 0;

  for (int t = 0; t < TS; ++t) {
    const short* src = (t & 1) ? hB : hA;
    short* dst = (t & 1) ? hA : hB;

    f32x4 c00 = {}, c01 = {}, c10 = {}, c11 = {};
    f32x4 c20 = {}, c21 = {}, c30 = {}, c31 = {};

    // ---- stage this wave's 16 frags of h-quarter q2 (sc0|sc1: read at L3) ----
#pragma unroll
    for (int j = 0; j < 16; ++j) {
      const int fi = sr * 16 + j;            // it = fi>>2, mtl = fi&3
      const int it = fi >> 2, mtl = fi & 3;
      const short* g = src + ((size_t)((by * 4 + mtl) * 32 + q2 * 16 + it)) * 512 + (size_t)l * 8;
      __builtin_amdgcn_global_load_lds((gas_void*)g,
                                       (las_void*)(sm + q2 * 32768 + fi * 512), 16, 0, 17);
    }
    asm volatile("s_waitcnt vmcnt(0)" ::: "memory");
    __builtin_amdgcn_s_barrier();

    // ---- 128 MFMA/wave on own quarter; x-waves apply in-register relu ----
    if (t > 0 || w4 >= 2) {
      const short* cb = sm + q2 * 32768;
#pragma unroll
      for (int it = 0; it < 16; ++it) {
        const short* fb = cb + it * 2048 + l * 8;
        s16x8 a0 = *(const s16x8*)(fb);
        s16x8 a1 = *(const s16x8*)(fb + 512);
        s16x8 a2 = *(const s16x8*)(fb + 1024);
        s16x8 a3 = *(const s16x8*)(fb + 1536);
        if (w4 < 2) { a0 = relu8(a0); a1 = relu8(a1); a2 = relu8(a2); a3 = relu8(a3); }
        const s16x8 w0 = W[it * 2], w1 = W[it * 2 + 1];
        c00 = MF(a0, w0, c00); c01 = MF(a0, w1, c01);
        c10 = MF(a1, w0, c10); c11 = MF(a1, w1, c11);
        c20 = MF(a2, w0, c20); c21 = MF(a2, w1, c21);
        c30 = MF(a3, w0, c30); c31 = MF(a3, w1, c31);
      }
    }
    __builtin_amdgcn_s_barrier();  // all LDS reads done before red overwrites [0,64K)

    // ---- partials to LDS: slot s = mtl*2+gi at float ((s*512 + w*64 + l)*4) ----
    {
      float* base = red + (size_t)(w * 64 + l) * 4;
      *(f32x4*)(base + 0 * 2048) = c00;
      *(f32x4*)(base + 1 * 2048) = c01;
      *(f32x4*)(base + 2 * 2048) = c10;
      *(f32x4*)(base + 3 * 2048) = c11;
      *(f32x4*)(base + 4 * 2048) = c20;
      *(f32x4*)(base + 5 * 2048) = c21;
      *(f32x4*)(base + 6 * 2048) = c30;
      *(f32x4*)(base + 7 * 2048) = c31;
    }
    __syncthreads();

    // ---- epilogue: 2 cells/thread, c-state in registers ----
#pragma unroll
    for (int cc2 = 0; cc2 < 2; ++cc2) {
      const int mloc = mloc0 + cc2 * 32;
      const int mtl = mloc >> 4, qq = (mloc & 15) >> 2, jj = mloc & 3;
      const int lane = qq * 16 + hc;
      float g4[4];
#pragma unroll
      for (int g = 0; g < 4; ++g) {
        const int s = mtl * 2 + (g & 1);
        const int wv = (g >> 1) * 4;
        float sum = 0.f;
#pragma unroll
        for (int k2 = 0; k2 < 4; ++k2)
          sum += red[(size_t)(s * 512 + (wv + k2) * 64 + lane) * 4 + jj];
        g4[g] = sum;
      }
      float gi_ = g4[0] + bs0;
      float gf = g4[1] + bs1;
      float gg = g4[2] + bs2;
      float go = g4[3] + bs3;
      if (t == 0) { gi_ += xg0; gf += xg1; gg += xg2; go += xg3; }
      float cn = sigm(gf) * creg[cc2] + sigm(gi_) * tanh_f(gg);
      creg[cc2] = cn;
      float h = sigm(go) * tanh_f(cn);
      short h16 = f2b(h);
      // agent-scope (sc1) stores: write through to coherence point, no fence needed
      __hip_atomic_store(dst + hIdx[cc2], h16, __ATOMIC_RELAXED, __HIP_MEMORY_SCOPE_AGENT);
      __hip_atomic_store(hsC + (size_t)tslot * BD * HD + idxA[cc2], h16,
                         __ATOMIC_RELAXED, __HIP_MEMORY_SCOPE_AGENT);
      if (t == TS - 1) { o_h[idxA[cc2]] = h; o_c[idxA[cc2]] = cn; }
    }
    if (++tslot == CH) tslot = 0;

    // ---- per-by grid barrier: h(t+1) visible to all same-by blocks ----
    grid_bar(s1, (unsigned)(t + 1), bx);

    // ---- fused out_proj phase every CH steps ----
    if (tslot == 0) {
      if (bx < 2 * CH) {
        const int tloc = bx >> 1, nj = bx & 1;
        const int tglob = t + 1 - CH + tloc;
        const short* hsrc = hsC + (size_t)tloc * BD * HD + (size_t)by * 64 * HD;
        const int amt = w & 3, nfh = w >> 2;
        f32x4 p0 = {}, p1 = {};
#pragma unroll
        for (int cc = 0; cc < 2; ++cc) {
#pragma unroll
          for (int j = 0; j < 8; ++j) {
            const int fi = w * 8 + j;
            const int it = fi >> 2, ml = fi & 3;
            const short* g = hsrc + (size_t)(ml * 16 + r) * HD + (cc * 16 + it) * 32 + q * 8;
            __builtin_amdgcn_global_load_lds((gas_void*)g, (las_void*)(sm + fi * 512), 16, 0, 17);
          }
          asm volatile("s_waitcnt vmcnt(0)" ::: "memory");
          __syncthreads();
#pragma unroll
          for (int itl = 0; itl < 16; ++itl) {
            const short* fb = sm + itl * 2048 + amt * 512 + l * 8;
            s16x8 a = *(const s16x8*)(fb);
            const int kk = (cc * 16 + itl) * 32 + q * 8;
            s16x8 b0 = *(const s16x8*)(outw + (size_t)(nj * 64 + nfh * 32 + r) * HD + kk);
            s16x8 b1 = *(const s16x8*)(outw + (size_t)(nj * 64 + nfh * 32 + 16 + r) * HD + kk);
            p0 = MF(a, b0, p0);
            p1 = MF(a, b1, p1);
          }
          __syncthreads();
        }
#pragma unroll
        for (int f2 = 0; f2 < 2; ++f2) {
          const int col = nj * 64 + nfh * 32 + f2 * 16 + r;
          const float bb = outb[col];
          const f32x4 pa = f2 ? p1 : p0;
#pragma unroll
          for (int j2 = 0; j2 < 4; ++j2) {
            const int brow = by * 64 + amt * 16 + q * 4 + j2;
            dout[((size_t)brow * TS + tglob) * OD + col] = pa[j2] + bb;
          }
        }
      }
      ++pcnt;
      // nobody overwrites hsC slot 0 before this by-group's phase reads finish
      grid_bar(s2, pcnt, bx);
    }
  }
}

extern "C" void kernel_launch(void* const* d_in, const int* in_sizes, int n_in,
                              void* d_out, int out_size, void* d_ws, size_t ws_size,
                              hipStream_t stream) {
  static const int exp_sizes[26] = {
      131072, 131072, 128, 524288, 1024, 524288, 1024, 131072, 1024,
      4194304, 4194304, 4096, 4096, 131072, 128, 524288, 1024, 1024, 1,
      524288, 1024, 1048576, 1024, 2048, 2, 1};
  if (n_in < 26) return;
  for (int i = 0; i < 26; ++i)
    if (in_sizes[i] != exp_sizes[i]) return;

  const float* enc_out = (const float*)d_in[0];
  const float* enc_hid = (const float*)d_in[1];
  const float* start_tok = (const float*)d_in[2];
  const float* l2h_w = (const float*)d_in[3];
  const float* l2h_b = (const float*)d_in[4];
  const float* l2h2_w = (const float*)d_in[5];
  const float* l2h2_b = (const float*)d_in[6];
  const float* emb_w = (const float*)d_in[7];
  const float* emb_b = (const float*)d_in[8];
  const float* Wih_f = (const float*)d_in[9];
  const float* Whh_f = (const float*)d_in[10];
  const float* bih = (const float*)d_in[11];
  const float* bhh = (const float*)d_in[12];
  const float* outw_f = (const float*)d_in[13];
  const float* outb = (const float*)d_in[14];
  const float* seq_w = (const float*)d_in[15];
  const float* seq_b = (const float*)d_in[16];
  const float* seq2_w = (const float*)d_in[17];
  const float* seq2_b = (const float*)d_in[18];
  const float* mass_w = (const float*)d_in[19];
  const float* mass_b = (const float*)d_in[20];
  const float* mass2_w = (const float*)d_in[21];
  const float* mass2_b = (const float*)d_in[22];
  const float* mass3_w = (const float*)d_in[23];
  const float* mass3_b = (const float*)d_in[24];

  // ---- workspace layout ----
  char* p = (char*)d_ws;
  float* c_buf = (float*)p;  p += (size_t)BD * HD * 4;        // 1 MB
  float* bsum = (float*)p;   p += (size_t)4 * HD * 4;         // 16 KB
  float* xg = (float*)p;     p += (size_t)4 * HD * 4;         // 16 KB
  float* n1 = (float*)p;     p += (size_t)BD * HD * 4;        // 1 MB
  short* m1 = (short*)p;     p += (size_t)BD * HD * 2;        // 512 KB
  short* m2 = (short*)p;     p += (size_t)BD * HD * 2;        // 512 KB
  short* xrow = (short*)p;   p += (size_t)HD * 2;             // 2 KB
  short* hA = (short*)p;     p += (size_t)BD * HD * 2;        // 512 KB
  short* hB = (short*)p;     p += (size_t)BD * HD * 2;        // 512 KB
  short* Wt = (short*)p;     p += (size_t)4 * HD * KC * 2;    // 16 MB
  short* outw = (short*)p;   p += (size_t)OD * HD * 2;        // 256 KB
  unsigned* ctrs = (unsigned*)p; p += 2048;                   // 4 by x 128 words
  short* hsC = (short*)p;    // CH * BD * HD bf16
  size_t fixed_bytes = (size_t)(p - (char*)d_ws);
  const size_t step_bytes = (size_t)BD * HD * 2;
  int CH = 0;
  const int cands[7] = {25, 20, 10, 5, 4, 2, 1};
  for (int ci = 0; ci < 7; ++ci) {
    if (fixed_bytes + (size_t)cands[ci] * step_bytes <= ws_size) { CH = cands[ci]; break; }
  }
  if (CH == 0) return;

  float* dout = (float*)d_out;
  float* o_dec = dout;                       // [B][TS][OD]
  float* o_h = dout + (size_t)BD * TS * OD;  // [1][B][HD]
  float* o_c = o_h + (size_t)BD * HD;        // [1][B][HD]
  float* o_num = o_c + (size_t)BD * HD;      // [B][1]
  float* o_mass = o_num + BD;                // [B][2]

  // prep
  wrep_k<<<4096, 256, 0, stream>>>(Wih_f, Whh_f, Wt);
  cvt8_k<<<OD * HD / 2048, 256, 0, stream>>>(outw_f, outw);
  bsum_k<<<16, 256, 0, stream>>>(bih, bhh, bsum);
  x0_k<<<4, 256, 0, stream>>>(start_tok, emb_w, emb_b, xrow);
  xg_k<<<1024, 256, 0, stream>>>(xrow, Wih_f, xg);
  zero_ctr_k<<<1, 512, 0, stream>>>(ctrs);

  // heads + initial state
  dim3 fcg(16, 4);
  fc_mfma<LATD, false, 2><<<fcg, 256, 0, stream>>>(enc_hid, l2h_w, l2h_b, hA, 0, 0);
  fc_mfma<LATD, false, 0><<<fcg, 256, 0, stream>>>(enc_hid, l2h2_w, l2h2_b, c_buf, 0, 0);
  fc_mfma<LATD, false, 0><<<fcg, 256, 0, stream>>>(enc_out, seq_w, seq_b, n1, 0, 0);
  fc_mfma<LATD, false, 1><<<fcg, 256, 0, stream>>>(enc_out, mass_w, mass_b, m1, HD, 0);
  fc_mfma<HD, true, 1><<<fcg, 256, 0, stream>>>(m1, mass2_w, mass2_b, m2, HD, 0);
  num_k<<<64, 256, 0, stream>>>(n1, seq2_w, seq2_b, o_num);
  mass_k<<<64, 256, 0, stream>>>(m2, mass3_w, mass3_b, o_mass);

  // whole LSTM scan + output projection in ONE persistent launch
  lstm_persist<<<dim3(64, 4), 512, 0, stream>>>(
      hA, hB, c_buf, Wt, bsum, xg, hsC, outw, outb, o_dec, o_h, o_c, ctrs, CH);
}